// Round 14
// baseline (232.776 us; speedup 1.0000x reference)
//
#include <hip/hip_runtime.h>

#define NB 8
#define NS 1024
#define NH 32
#define NKV 8
#define ND 128
#define KT 64

typedef _Float16 f16x8 __attribute__((ext_vector_type(8)));
typedef __fp16 fp16x2 __attribute__((ext_vector_type(2)));
typedef float f32x16 __attribute__((ext_vector_type(16)));
typedef unsigned int u32x2 __attribute__((ext_vector_type(2)));

__device__ __forceinline__ float exp2fast(float x) { return __builtin_amdgcn_exp2f(x); }
__device__ __forceinline__ unsigned pkrtz_u(float a, float b) {
  union { fp16x2 h; unsigned u; } c;
  c.h = __builtin_amdgcn_cvt_pkrtz(a, b);
  return c.u;
}
__device__ __forceinline__ u32x2 swap32(float x) {
  union { float f; unsigned u; } c; c.f = x;
  return __builtin_amdgcn_permlane32_swap(c.u, c.u, false, false);
}
__device__ __forceinline__ float asf(unsigned u) { union { unsigned u; float f; } c; c.u = u; return c.f; }

// ---- pre-pass A: K f32 [t][dkv] -> fragment-ordered f16 panels ----
// wsK layout: [panel=b*8+hkv][ti(16)][chunk=kb*8+dblk (16)][lane(64)][16B]
__global__ __launch_bounds__(256)
void cvt_kf(const float* __restrict__ kg, char* __restrict__ wsK)
{
  int g = blockIdx.x * 256 + threadIdx.x;      // one 16B f16 chunk each
  int t = g >> 7, c8 = g & 127;
  int hkv = c8 >> 4, d8 = c8 & 15;
  const float* src = kg + (size_t)t * 1024 + hkv * 128 + d8 * 8;
  float4 a = *(const float4*)src;
  float4 c = *(const float4*)(src + 4);
  f16x8 h8;
  h8[0] = (_Float16)a.x; h8[1] = (_Float16)a.y; h8[2] = (_Float16)a.z; h8[3] = (_Float16)a.w;
  h8[4] = (_Float16)c.x; h8[5] = (_Float16)c.y; h8[6] = (_Float16)c.z; h8[7] = (_Float16)c.w;
  int b  = t >> 10, kv = t & 1023;
  int ti = kv >> 6, kvl = kv & 63, kb = kvl >> 5, lq = kvl & 31;
  int dblk = d8 >> 1, hi = d8 & 1;
  size_t off = (((size_t)(b * 8 + hkv) * 16 + ti) * 16 + kb * 8 + dblk) * 1024 + (hi * 32 + lq) * 16;
  *(f16x8*)(wsK + off) = h8;
}

// ---- pre-pass B: V f32 -> fragment-ordered V^T f16 panels ----
// wsV layout: [panel][ti(16)][chunk=t*4+nb (16)][lane(64)][16B]
__global__ __launch_bounds__(256)
void cvt_vf(const float* __restrict__ vg, _Float16* __restrict__ wsV)
{
  __shared__ _Float16 T[ND][KT];               // 16 KB transpose tile
  const int tid = threadIdx.x;
  const int kvt = blockIdx.x, b = blockIdx.y, hkv = blockIdx.z;
#pragma unroll
  for (int pass = 0; pass < 8; ++pass) {
    int kvr = (tid >> 5) + pass * 8;
    int d4  = (tid & 31) * 4;
    float4 v = ((const float4*)vg)[(size_t)(b * NS + kvt * KT + kvr) * 256 + hkv * 32 + (tid & 31)];
    T[d4 + 0][kvr] = (_Float16)v.x;
    T[d4 + 1][kvr] = (_Float16)v.y;
    T[d4 + 2][kvr] = (_Float16)v.z;
    T[d4 + 3][kvr] = (_Float16)v.w;
  }
  __syncthreads();
  _Float16* out = wsV + ((size_t)(b * 8 + hkv) * 16 + kvt) * 8192;
#pragma unroll
  for (int pass = 0; pass < 4; ++pass) {
    int unit = tid + pass * 256;
    int c = unit >> 6, lane = unit & 63;
    int d = (c & 3) * 32 + (lane & 31);
    int kv8 = (c >> 2) * 16 + (lane >> 5) * 8;
    *(f16x8*)(out + unit * 8) = *(const f16x8*)&T[d][kv8];
  }
}

// softmax + P->A-frag for one 32-row block; updates m,l,acc in place, emits pa[4]
__device__ __forceinline__ void softmax_block(f32x16& s0, f32x16& s1, float& m_run, float& l_run,
                                              f32x16* acc, f16x8* pa, int hi)
{
  float pmax = s0[0];
#pragma unroll
  for (int r = 1; r < 16; ++r) pmax = fmaxf(pmax, s0[r]);
#pragma unroll
  for (int r = 0; r < 16; ++r) pmax = fmaxf(pmax, s1[r]);
  {
    u32x2 pr = swap32(pmax);
    pmax = fmaxf(asf(pr[0]), asf(pr[1]));
  }
  const int need = !__all(pmax <= m_run + 8.0f);
  if (need) {
    const float mn = fmaxf(m_run, pmax);
    const float al = exp2fast(m_run - mn);
    m_run = mn;
#pragma unroll
    for (int r = 0; r < 16; ++r) {
      int row = (r & 3) + 8 * (r >> 2) + 4 * hi;
      float a = __shfl(al, row, 64);
#pragma unroll
      for (int nb = 0; nb < 4; ++nb) acc[nb][r] *= a;
    }
    l_run *= al;
  }
  float rs = 0.f;
#pragma unroll
  for (int r = 0; r < 16; ++r) {
    float p = exp2fast(s0[r] - m_run);
    s0[r] = p; rs += p;
  }
#pragma unroll
  for (int r = 0; r < 16; ++r) {
    float p = exp2fast(s1[r] - m_run);
    s1[r] = p; rs += p;
  }
  {
    u32x2 sr = swap32(rs);
    rs = asf(sr[0]) + asf(sr[1]);
  }
  l_run += rs;
#pragma unroll
  for (int t = 0; t < 4; ++t) {
    const f32x16& sk = (t < 2) ? s0 : s1;
    const int rb = (t & 1) * 8;
    unsigned w0 = pkrtz_u(sk[rb + 0], sk[rb + 1]);
    unsigned w1 = pkrtz_u(sk[rb + 2], sk[rb + 3]);
    unsigned w2 = pkrtz_u(sk[rb + 4], sk[rb + 5]);
    unsigned w3 = pkrtz_u(sk[rb + 6], sk[rb + 7]);
    u32x2 p02 = __builtin_amdgcn_permlane32_swap(w0, w2, false, false);
    u32x2 p13 = __builtin_amdgcn_permlane32_swap(w1, w3, false, false);
    union { unsigned u[4]; f16x8 v; } pw;
    pw.u[0] = p02[0]; pw.u[1] = p13[0]; pw.u[2] = p02[1]; pw.u[3] = p13[1];
    pa[t] = pw.v;
  }
}

// ---- attention: barrier-free, LDS-free; 64 q-rows per wave (2 row-blocks share K/V frags) ----
__global__ __launch_bounds__(256, 1)
void attn_fwd(const float* __restrict__ qg, const char* __restrict__ wsK,
              const char* __restrict__ wsV, float* __restrict__ og)
{
  // 512 blocks; xcd=id&7 gets panels xcd*8..+7 (4MB) in its L2
  const int id = blockIdx.x;
  const int v  = (id & 7) * 64 + (id >> 3);
  const int panel = v >> 3;                     // b*8+hkv
  const int sub   = v & 7;
  const int b     = panel >> 3;
  const int hkv   = panel & 7;
  const int h     = hkv * 4 + (sub & 3);
  const int p     = sub >> 2;                   // pair index 0..1 -> qtiles {p, 3-p}

  const int tid  = threadIdx.x;
  const int lane = tid & 63;
  const int w    = tid >> 6;
  const int lq   = lane & 31;
  const int hi   = lane >> 5;

  const float QS = 0.08838834764831845f * 1.4426950408889634f;  // scale * log2(e)

  const char* wsKb = wsK + (size_t)panel * 16 * 16384;
  const char* wsVb = wsV + (size_t)panel * 16 * 16384;

#pragma unroll 1
  for (int ph = 0; ph < 2; ++ph) {
    const int qtile = ph ? (3 - p) : p;
    const int wv    = ph ? (3 - w) : w;         // swap wave->rows so per-wave totals are uniform (17)
    const int qr0   = qtile * 256 + wv * 64;    // wave's first q-row (64 rows)

    // ---- Q fragments for both row-blocks ----
    f16x8 qfa[8], qfb[8];
    {
      const float* qpA = qg + (size_t)(b * NS + qr0 + lq) * (NH * ND) + h * ND + hi * 8;
      const float* qpB = qpA + (size_t)32 * (NH * ND);
#pragma unroll
      for (int dblk = 0; dblk < 8; ++dblk) {
        float4 f0 = *(const float4*)(qpA + dblk * 16);
        float4 f1 = *(const float4*)(qpA + dblk * 16 + 4);
        f16x8 a;
        a[0] = (_Float16)(f0.x * QS); a[1] = (_Float16)(f0.y * QS);
        a[2] = (_Float16)(f0.z * QS); a[3] = (_Float16)(f0.w * QS);
        a[4] = (_Float16)(f1.x * QS); a[5] = (_Float16)(f1.y * QS);
        a[6] = (_Float16)(f1.z * QS); a[7] = (_Float16)(f1.w * QS);
        qfa[dblk] = a;
        float4 g0 = *(const float4*)(qpB + dblk * 16);
        float4 g1 = *(const float4*)(qpB + dblk * 16 + 4);
        f16x8 c;
        c[0] = (_Float16)(g0.x * QS); c[1] = (_Float16)(g0.y * QS);
        c[2] = (_Float16)(g0.z * QS); c[3] = (_Float16)(g0.w * QS);
        c[4] = (_Float16)(g1.x * QS); c[5] = (_Float16)(g1.y * QS);
        c[6] = (_Float16)(g1.z * QS); c[7] = (_Float16)(g1.w * QS);
        qfb[dblk] = c;
      }
    }

    f32x16 accA[4], accB[4];
#pragma unroll
    for (int nb = 0; nb < 4; ++nb)
#pragma unroll
      for (int r = 0; r < 16; ++r) { accA[nb][r] = 0.f; accB[nb][r] = 0.f; }
    float mA = -1e30f, lA = 0.f, mB = -1e30f, lB = 0.f;

    const int nt = qtile * 4 + wv + 1;
    for (int ti = 0; ti < nt; ++ti) {
      const char* kt  = wsKb + (size_t)ti * 16384;
      const char* vt_ = wsVb + (size_t)ti * 16384;

      // ---- K fragments (shared by both row-blocks) ----
      f16x8 kf[16];
#pragma unroll
      for (int c = 0; c < 16; ++c)
        kf[c] = *(const f16x8*)(kt + c * 1024 + lane * 16);

      // ---- swapped QK^T for both row-blocks (4 independent chains) ----
      f32x16 sA0, sA1, sB0, sB1;
#pragma unroll
      for (int r = 0; r < 16; ++r) { sA0[r] = 0.f; sA1[r] = 0.f; sB0[r] = 0.f; sB1[r] = 0.f; }
      __builtin_amdgcn_s_setprio(1);
#pragma unroll
      for (int dblk = 0; dblk < 8; ++dblk) {
        sA0 = __builtin_amdgcn_mfma_f32_32x32x16_f16(kf[dblk],     qfa[dblk], sA0, 0, 0, 0);
        sA1 = __builtin_amdgcn_mfma_f32_32x32x16_f16(kf[8 + dblk], qfa[dblk], sA1, 0, 0, 0);
        sB0 = __builtin_amdgcn_mfma_f32_32x32x16_f16(kf[dblk],     qfb[dblk], sB0, 0, 0, 0);
        sB1 = __builtin_amdgcn_mfma_f32_32x32x16_f16(kf[8 + dblk], qfb[dblk], sB1, 0, 0, 0);
      }
      __builtin_amdgcn_s_setprio(0);

      // ---- V fragments issued now: latency hides under 2x softmax ----
      f16x8 vf[16];
#pragma unroll
      for (int c = 0; c < 16; ++c)
        vf[c] = *(const f16x8*)(vt_ + c * 1024 + lane * 16);

      // ---- causal mask (final tile only; kv0 == qr0 there) ----
      if (ti == nt - 1) {
        const int kv0 = ti * KT;
        const int thrA = (qr0 + lq) - kv0;         // in [0,31] on the diagonal tile
        const int thrB = thrA + 32;
#pragma unroll
        for (int r = 0; r < 16; ++r) {
          int kvl0 = (r & 3) + 8 * (r >> 2) + 4 * hi;
          int kvl1 = 32 + kvl0;
          if (kvl0 > thrA) sA0[r] = -1e30f;
          if (kvl1 > thrA) sA1[r] = -1e30f;
          if (kvl0 > thrB) sB0[r] = -1e30f;
          if (kvl1 > thrB) sB1[r] = -1e30f;
        }
      }

      // ---- softmax both row-blocks ----
      f16x8 paA[4], paB[4];
      softmax_block(sA0, sA1, mA, lA, accA, paA, hi);
      softmax_block(sB0, sB1, mB, lB, accB, paB, hi);

      // ---- O += P V (both row-blocks share vf) ----
      __builtin_amdgcn_s_setprio(1);
#pragma unroll
      for (int t = 0; t < 4; ++t)
#pragma unroll
        for (int nb = 0; nb < 4; ++nb) {
          accA[nb] = __builtin_amdgcn_mfma_f32_32x32x16_f16(paA[t], vf[t * 4 + nb], accA[nb], 0, 0, 0);
          accB[nb] = __builtin_amdgcn_mfma_f32_32x32x16_f16(paB[t], vf[t * 4 + nb], accB[nb], 0, 0, 0);
        }
      __builtin_amdgcn_s_setprio(0);
    }

    // ---- epilogue: divide by l, coalesced f32 stores ----
    const float liA = 1.0f / lA, liB = 1.0f / lB;
#pragma unroll
    for (int r = 0; r < 16; ++r) {
      int row = (r & 3) + 8 * (r >> 2) + 4 * hi;
      float a = __shfl(liA, row, 64);
      float c = __shfl(liB, row, 64);
      float* opA = og + (size_t)(b * NS + qr0 + row) * (NH * ND) + h * ND + lq;
      float* opB = opA + (size_t)32 * (NH * ND);
#pragma unroll
      for (int nb = 0; nb < 4; ++nb) {
        opA[nb * 32] = accA[nb][r] * a;
        opB[nb * 32] = accB[nb][r] * c;
      }
    }
  }
}

extern "C" void kernel_launch(void* const* d_in, const int* in_sizes, int n_in,
                              void* d_out, int out_size, void* d_ws, size_t ws_size,
                              hipStream_t stream) {
  const float* q = (const float*)d_in[0];
  const float* k = (const float*)d_in[1];
  const float* v = (const float*)d_in[2];
  float* o = (float*)d_out;

  const size_t KSZ = (size_t)NB * NKV * NS * ND * sizeof(_Float16);  // 16.78 MB each
  if (ws_size < 2 * KSZ) return;     // fail loudly (output stays poisoned)
  char*     wsK = (char*)d_ws;
  _Float16* wsV = (_Float16*)((char*)d_ws + KSZ);

  cvt_kf<<<dim3((NB * NS * 128) / 256), 256, 0, stream>>>(k, wsK);
  cvt_vf<<<dim3(NS / KT, NB, NKV),      256, 0, stream>>>(v, wsV);
  attn_fwd<<<dim3(512),                 256, 0, stream>>>(q, wsK, (const char*)wsV, o);
}

// Round 15
// 201.563 us; speedup vs baseline: 1.1549x; 1.1549x over previous
//
#include <hip/hip_runtime.h>

#define NB 8
#define NS 1024
#define NH 32
#define NKV 8
#define ND 128
#define KT 32

typedef _Float16 f16x8 __attribute__((ext_vector_type(8)));
typedef __fp16 fp16x2 __attribute__((ext_vector_type(2)));
typedef float f32x16 __attribute__((ext_vector_type(16)));
typedef unsigned int u32x2 __attribute__((ext_vector_type(2)));

__device__ __forceinline__ float exp2fast(float x) { return __builtin_amdgcn_exp2f(x); }
__device__ __forceinline__ unsigned pkrtz_u(float a, float b) {
  union { fp16x2 h; unsigned u; } c;
  c.h = __builtin_amdgcn_cvt_pkrtz(a, b);
  return c.u;
}
__device__ __forceinline__ u32x2 swap32(float x) {
  union { float f; unsigned u; } c; c.f = x;
  return __builtin_amdgcn_permlane32_swap(c.u, c.u, false, false);
}
__device__ __forceinline__ float asf(unsigned u) { union { unsigned u; float f; } c; c.u = u; return c.f; }

// ---- pre-pass A: K f32 [t][dkv] -> fragment-ordered f16 panels, 32-kv tiles ----
// wsK layout: [panel=b*8+hkv][ti(32)][dblk(8)][lane(64)][16B]
// lane=hi*32+lq holds K[kv=ti*32+lq][d=dblk*16+hi*8 .. +8]
__global__ __launch_bounds__(256)
void cvt_kf(const float* __restrict__ kg, char* __restrict__ wsK)
{
  int g = blockIdx.x * 256 + threadIdx.x;      // one 16B f16 chunk each
  int t = g >> 7, c8 = g & 127;
  int hkv = c8 >> 4, d8 = c8 & 15;
  const float* src = kg + (size_t)t * 1024 + hkv * 128 + d8 * 8;
  float4 a = *(const float4*)src;
  float4 c = *(const float4*)(src + 4);
  f16x8 h8;
  h8[0] = (_Float16)a.x; h8[1] = (_Float16)a.y; h8[2] = (_Float16)a.z; h8[3] = (_Float16)a.w;
  h8[4] = (_Float16)c.x; h8[5] = (_Float16)c.y; h8[6] = (_Float16)c.z; h8[7] = (_Float16)c.w;
  int b  = t >> 10, kv = t & 1023;
  int ti = kv >> 5, lq = kv & 31;
  int dblk = d8 >> 1, hi = d8 & 1;
  size_t off = (((size_t)(b * 8 + hkv) * 32 + ti) * 8 + dblk) * 1024 + (hi * 32 + lq) * 16;
  *(f16x8*)(wsK + off) = h8;
}

// ---- pre-pass B: V f32 -> fragment-ordered V^T f16 panels, 32-kv tiles ----
// wsV layout: [panel][ti(32)][chunk=t*4+nb (8)][lane(64)][16B]
// lane=hi*32+lq holds V^T[d=nb*32+lq][kv=ti*32+t*16+hi*8 .. +8]
__global__ __launch_bounds__(256)
void cvt_vf(const float* __restrict__ vg, _Float16* __restrict__ wsV)
{
  __shared__ _Float16 T[ND][64];               // 16 KB transpose tile (64 kv)
  const int tid = threadIdx.x;
  const int kvt = blockIdx.x, b = blockIdx.y, hkv = blockIdx.z;   // kvt: 16 blocks of 64 kv
#pragma unroll
  for (int pass = 0; pass < 8; ++pass) {
    int kvr = (tid >> 5) + pass * 8;
    int d4  = (tid & 31) * 4;
    float4 v = ((const float4*)vg)[(size_t)(b * NS + kvt * 64 + kvr) * 256 + hkv * 32 + (tid & 31)];
    T[d4 + 0][kvr] = (_Float16)v.x;
    T[d4 + 1][kvr] = (_Float16)v.y;
    T[d4 + 2][kvr] = (_Float16)v.z;
    T[d4 + 3][kvr] = (_Float16)v.w;
  }
  __syncthreads();
  _Float16* out = wsV + ((size_t)(b * 8 + hkv) * 32 + kvt * 2) * 4096;
#pragma unroll
  for (int pass = 0; pass < 4; ++pass) {
    int unit = tid + pass * 256;               // 1024 units = 2 tiles x 8 chunks x 64 lanes
    int tis = unit >> 9, rem = unit & 511;
    int c = rem >> 6, lane = rem & 63;
    int d = (c & 3) * 32 + (lane & 31);
    int kv8 = tis * 32 + (c >> 2) * 16 + (lane >> 5) * 8;
    *(f16x8*)(out + (size_t)tis * 4096 + (c * 64 + lane) * 8) = *(const f16x8*)&T[d][kv8];
  }
}

// ---- attention: barrier-free, LDS-free, KT=32 (small per-tile reg state -> 2 waves/SIMD) ----
__global__ __launch_bounds__(256, 1)
void attn_fwd(const float* __restrict__ qg, const char* __restrict__ wsK,
              const char* __restrict__ wsV, float* __restrict__ og)
{
  // 1024 blocks; xcd=id&7 gets contiguous panels (4MB K+V f16) in its L2
  const int id = blockIdx.x;
  const int v  = (id & 7) * 128 + (id >> 3);
  const int panel = v >> 4;                     // b*8+hkv
  const int sub   = v & 15;
  const int b     = panel >> 3;
  const int hkv   = panel & 7;
  const int h     = hkv * 4 + (sub & 3);
  const int p     = sub >> 2;                   // 0..3 -> qtile pair {p, 7-p}

  const int tid  = threadIdx.x;
  const int lane = tid & 63;
  const int w    = tid >> 6;
  const int lq   = lane & 31;
  const int hi   = lane >> 5;

  const float QS = 0.08838834764831845f * 1.4426950408889634f;  // scale * log2(e)

  const char* wsKb = wsK + (size_t)panel * 32 * 8192;
  const char* wsVb = wsV + (size_t)panel * 32 * 8192;

#pragma unroll 1
  for (int ph = 0; ph < 2; ++ph) {
    const int qtile = ph ? (7 - p) : p;
    const int wv    = ph ? (3 - w) : w;         // wave-row swap: total trips = 33, uniform
    const int qr0w  = qtile * 128 + wv * 32;
    const int qrow  = qr0w + lq;

    // ---- Q fragments (B-frag: col=q=lane&31, k = 8*hi + i per 16-d block) ----
    f16x8 qf[8];
    {
      const float* qp = qg + (size_t)(b * NS + qrow) * (NH * ND) + h * ND + hi * 8;
#pragma unroll
      for (int dblk = 0; dblk < 8; ++dblk) {
        float4 f0 = *(const float4*)(qp + dblk * 16);
        float4 f1 = *(const float4*)(qp + dblk * 16 + 4);
        f16x8 a;
        a[0] = (_Float16)(f0.x * QS); a[1] = (_Float16)(f0.y * QS);
        a[2] = (_Float16)(f0.z * QS); a[3] = (_Float16)(f0.w * QS);
        a[4] = (_Float16)(f1.x * QS); a[5] = (_Float16)(f1.y * QS);
        a[6] = (_Float16)(f1.z * QS); a[7] = (_Float16)(f1.w * QS);
        qf[dblk] = a;
      }
    }

    f32x16 acc[4];
#pragma unroll
    for (int nb = 0; nb < 4; ++nb)
#pragma unroll
      for (int r = 0; r < 16; ++r) acc[nb][r] = 0.f;
    float m_run = -1e30f, l_run = 0.f;

    const int nt = qtile * 4 + wv + 1;          // 32-kv tiles up to & incl diagonal
#pragma unroll 1
    for (int ti = 0; ti < nt; ++ti) {
      const char* kt  = wsKb + (size_t)ti * 8192;
      const char* vt_ = wsVb + (size_t)ti * 8192;

      // ---- K fragments: 8 coalesced dwordx4 loads ----
      f16x8 kf[8];
#pragma unroll
      for (int c = 0; c < 8; ++c)
        kf[c] = *(const f16x8*)(kt + c * 1024 + lane * 16);

      // ---- swapped QK^T: P^T[kv 0..31][q 0..31] ----
      f32x16 s;
#pragma unroll
      for (int r = 0; r < 16; ++r) s[r] = 0.f;
      __builtin_amdgcn_s_setprio(1);
#pragma unroll
      for (int dblk = 0; dblk < 8; ++dblk)
        s = __builtin_amdgcn_mfma_f32_32x32x16_f16(kf[dblk], qf[dblk], s, 0, 0, 0);
      __builtin_amdgcn_s_setprio(0);

      // ---- V fragments issued now: latency hides under softmax ----
      f16x8 vf[8];
#pragma unroll
      for (int c = 0; c < 8; ++c)
        vf[c] = *(const f16x8*)(vt_ + c * 1024 + lane * 16);

      // ---- causal mask (diagonal tile: kv0 == qr0w, thr = lq) ----
      if (ti == nt - 1) {
#pragma unroll
        for (int r = 0; r < 16; ++r) {
          int kvl = (r & 3) + 8 * (r >> 2) + 4 * hi;
          if (kvl > lq) s[r] = -1e30f;
        }
      }

      // ---- online softmax with defer-max ----
      float pmax = s[0];
#pragma unroll
      for (int r = 1; r < 16; ++r) pmax = fmaxf(pmax, s[r]);
      {
        u32x2 pr = swap32(pmax);
        pmax = fmaxf(asf(pr[0]), asf(pr[1]));
      }
      const int need = !__all(pmax <= m_run + 8.0f);
      if (need) {
        const float mn = fmaxf(m_run, pmax);
        const float al = exp2fast(m_run - mn);
        m_run = mn;
#pragma unroll
        for (int r = 0; r < 16; ++r) {
          int row = (r & 3) + 8 * (r >> 2) + 4 * hi;
          float a = __shfl(al, row, 64);
#pragma unroll
          for (int nb = 0; nb < 4; ++nb) acc[nb][r] *= a;
        }
        l_run *= al;
      }
      float rs = 0.f;
#pragma unroll
      for (int r = 0; r < 16; ++r) {
        float pv = exp2fast(s[r] - m_run);
        s[r] = pv; rs += pv;
      }
      {
        u32x2 sr = swap32(rs);
        rs = asf(sr[0]) + asf(sr[1]);
      }
      l_run += rs;

      // ---- P -> A-fragments in-register ----
      f16x8 pa[2];
#pragma unroll
      for (int t = 0; t < 2; ++t) {
        const int rb = t * 8;
        unsigned w0 = pkrtz_u(s[rb + 0], s[rb + 1]);
        unsigned w1 = pkrtz_u(s[rb + 2], s[rb + 3]);
        unsigned w2 = pkrtz_u(s[rb + 4], s[rb + 5]);
        unsigned w3 = pkrtz_u(s[rb + 6], s[rb + 7]);
        u32x2 p02 = __builtin_amdgcn_permlane32_swap(w0, w2, false, false);
        u32x2 p13 = __builtin_amdgcn_permlane32_swap(w1, w3, false, false);
        union { unsigned u[4]; f16x8 v; } pw;
        pw.u[0] = p02[0]; pw.u[1] = p13[0]; pw.u[2] = p02[1]; pw.u[3] = p13[1];
        pa[t] = pw.v;
      }

      // ---- O += P V ----
      __builtin_amdgcn_s_setprio(1);
#pragma unroll
      for (int t = 0; t < 2; ++t)
#pragma unroll
        for (int nb = 0; nb < 4; ++nb)
          acc[nb] = __builtin_amdgcn_mfma_f32_32x32x16_f16(pa[t], vf[t * 4 + nb], acc[nb], 0, 0, 0);
      __builtin_amdgcn_s_setprio(0);
    }

    // ---- epilogue: divide by l, coalesced f32 stores ----
    const float linv = 1.0f / l_run;
#pragma unroll
    for (int r = 0; r < 16; ++r) {
      int row = (r & 3) + 8 * (r >> 2) + 4 * hi;
      float li = __shfl(linv, row, 64);
      float* op = og + (size_t)(b * NS + qr0w + row) * (NH * ND) + h * ND + lq;
#pragma unroll
      for (int nb = 0; nb < 4; ++nb)
        op[nb * 32] = acc[nb][r] * li;
    }
  }
}

extern "C" void kernel_launch(void* const* d_in, const int* in_sizes, int n_in,
                              void* d_out, int out_size, void* d_ws, size_t ws_size,
                              hipStream_t stream) {
  const float* q = (const float*)d_in[0];
  const float* k = (const float*)d_in[1];
  const float* v = (const float*)d_in[2];
  float* o = (float*)d_out;

  const size_t KSZ = (size_t)NB * NKV * NS * ND * sizeof(_Float16);  // 16.78 MB each
  if (ws_size < 2 * KSZ) return;     // fail loudly (output stays poisoned)
  char*     wsK = (char*)d_ws;
  _Float16* wsV = (_Float16*)((char*)d_ws + KSZ);

  cvt_kf<<<dim3((NB * NS * 128) / 256), 256, 0, stream>>>(k, wsK);
  cvt_vf<<<dim3(16, NB, NKV),           256, 0, stream>>>(v, wsV);
  attn_fwd<<<dim3(1024),                256, 0, stream>>>(q, wsK, (const char*)wsV, o);
}